// Round 1
// baseline (1163.145 us; speedup 1.0000x reference)
//
#include <hip/hip_runtime.h>
#include <math.h>

#define BS2 2
#define SEQ 2048
#define DIM 1024
#define NH 16
#define DPH 64
#define MTOT (BS2 * SEQ)   // 4096

// ---------------- fp32 tiled GEMM: C[M,1024] = A[M,1024] @ W[1024,1024] + bias ----------------
#define BMM 128
#define BNN 128
#define BKK 16
#define SA 132  // padded LDS stride (bank-conflict-free, keeps 16B alignment)

__device__ __forceinline__ void gemm_core(const float* __restrict__ A,
                                          const float* __restrict__ W,
                                          const float* __restrict__ bias,
                                          float* __restrict__ C)
{
    __shared__ float As[BKK * SA];  // transposed: [k][m]
    __shared__ float Bs[BKK * SA];  // natural:    [k][n]

    const int tid = threadIdx.x;
    const int bn = blockIdx.x * BNN;
    const int bm = blockIdx.y * BMM;
    const int tx = tid & 15, ty = tid >> 4;

    const int arow = tid >> 2;          // 0..63
    const int acv  = (tid & 3) << 2;    // 0,4,8,12
    const int brow = tid >> 5;          // 0..7
    const int bnv  = (tid & 31) << 2;   // 0..124

    float acc[8][8];
#pragma unroll
    for (int i = 0; i < 8; ++i)
#pragma unroll
        for (int j = 0; j < 8; ++j) acc[i][j] = 0.f;

    for (int kk = 0; kk < DIM; kk += BKK) {
        float4 a0 = *(const float4*)&A[(size_t)(bm + arow) * DIM + kk + acv];
        float4 a1 = *(const float4*)&A[(size_t)(bm + arow + 64) * DIM + kk + acv];
        float4 b0 = *(const float4*)&W[(size_t)(kk + brow) * DIM + bn + bnv];
        float4 b1 = *(const float4*)&W[(size_t)(kk + brow + 8) * DIM + bn + bnv];
        __syncthreads();
        As[(acv + 0) * SA + arow] = a0.x;
        As[(acv + 1) * SA + arow] = a0.y;
        As[(acv + 2) * SA + arow] = a0.z;
        As[(acv + 3) * SA + arow] = a0.w;
        As[(acv + 0) * SA + arow + 64] = a1.x;
        As[(acv + 1) * SA + arow + 64] = a1.y;
        As[(acv + 2) * SA + arow + 64] = a1.z;
        As[(acv + 3) * SA + arow + 64] = a1.w;
        *(float4*)&Bs[brow * SA + bnv] = b0;
        *(float4*)&Bs[(brow + 8) * SA + bnv] = b1;
        __syncthreads();
#pragma unroll
        for (int k = 0; k < BKK; ++k) {
            float4 xa0 = *(const float4*)&As[k * SA + ty * 4];
            float4 xa1 = *(const float4*)&As[k * SA + ty * 4 + 64];
            float4 xb0 = *(const float4*)&Bs[k * SA + tx * 4];
            float4 xb1 = *(const float4*)&Bs[k * SA + tx * 4 + 64];
            float am[8]  = {xa0.x, xa0.y, xa0.z, xa0.w, xa1.x, xa1.y, xa1.z, xa1.w};
            float bm8[8] = {xb0.x, xb0.y, xb0.z, xb0.w, xb1.x, xb1.y, xb1.z, xb1.w};
#pragma unroll
            for (int i = 0; i < 8; ++i)
#pragma unroll
                for (int j = 0; j < 8; ++j)
                    acc[i][j] = fmaf(am[i], bm8[j], acc[i][j]);
        }
    }

#pragma unroll
    for (int ih = 0; ih < 2; ++ih)
#pragma unroll
        for (int i = 0; i < 4; ++i) {
            int r = bm + ty * 4 + i + ih * 64;
#pragma unroll
            for (int jh = 0; jh < 2; ++jh) {
                int c = bn + tx * 4 + jh * 64;
                float4 o;
                o.x = acc[ih * 4 + i][jh * 4 + 0] + bias[c + 0];
                o.y = acc[ih * 4 + i][jh * 4 + 1] + bias[c + 1];
                o.z = acc[ih * 4 + i][jh * 4 + 2] + bias[c + 2];
                o.w = acc[ih * 4 + i][jh * 4 + 3] + bias[c + 3];
                *(float4*)&C[(size_t)r * DIM + c] = o;
            }
        }
}

__global__ __launch_bounds__(256) void qkv_gemm(
    const float* __restrict__ X,
    const float* __restrict__ Wq, const float* __restrict__ bq,
    const float* __restrict__ Wk, const float* __restrict__ bk,
    const float* __restrict__ Wv, const float* __restrict__ bv,
    float* __restrict__ Q, float* __restrict__ K, float* __restrict__ V)
{
    const float* W;
    const float* bias;
    float* C;
    if (blockIdx.z == 0)      { W = Wq; bias = bq; C = Q; }
    else if (blockIdx.z == 1) { W = Wk; bias = bk; C = K; }
    else                      { W = Wv; bias = bv; C = V; }
    gemm_core(X, W, bias, C);
}

__global__ __launch_bounds__(256) void o_gemm(
    const float* __restrict__ CTX, const float* __restrict__ Wo,
    const float* __restrict__ bo, float* __restrict__ Out)
{
    gemm_core(CTX, Wo, bo, Out);
}

// ---------------- per-(row,head) L2 normalization of q,k; q *= scale ----------------
__global__ __launch_bounds__(256) void norm_qk(float* __restrict__ Q,
                                               float* __restrict__ K,
                                               const float* __restrict__ scale_p)
{
    const int tid = threadIdx.x;
    const int lane = tid & 63;
    const int w = tid >> 6;
    const int g = blockIdx.x * 4 + w;          // 0 .. MTOT*NH-1
    const int row = g >> 4;
    const int h = g & 15;
    const size_t idx = (size_t)row * DIM + h * DPH + lane;
    const float scale = *scale_p;

    float q = Q[idx], k = K[idx];
    float sq = q * q, sk = k * k;
#pragma unroll
    for (int m = 1; m < 64; m <<= 1) {
        sq += __shfl_xor(sq, m);
        sk += __shfl_xor(sk, m);
    }
    float nq = fmaxf(sqrtf(sq), 1e-12f);
    float nk = fmaxf(sqrtf(sk), 1e-12f);
    Q[idx] = q / nq * scale;
    K[idx] = k / nk;
}

// ---------------- flash-style attention, fp32 ----------------
#define PSS 64  // P-tile LDS stride

__global__ __launch_bounds__(256) void attn(
    const float* __restrict__ Q, const float* __restrict__ K,
    const float* __restrict__ V, const int* __restrict__ mask,
    float* __restrict__ CTX)
{
    __shared__ float Qs[DPH * 64];   // [d][r]  (transposed)
    __shared__ float Ks[DPH * 64];   // [d][c]  (transposed)
    __shared__ float Vs[64 * DPH];   // [c][d]  (natural)
    __shared__ float Ps[64 * PSS];   // [r][c]

    const int tid = threadIdx.x;
    const int qt = blockIdx.x;   // 0..31
    const int h  = blockIdx.y;   // 0..15
    const int b  = blockIdx.z;   // 0..1

    const int rq = tid >> 4;     // 0..15 -> rows rq*4..rq*4+3
    const int cq = tid & 15;     // 0..15 -> cols cq*4..cq*4+3

    const float* Qbase = Q + (size_t)(b * SEQ + qt * 64) * DIM + h * DPH;
#pragma unroll
    for (int i = 0; i < 4; ++i) {
        int idx = i * 256 + tid;
        int r = idx >> 4, cv = (idx & 15) << 2;
        float4 v = *(const float4*)&Qbase[(size_t)r * DIM + cv];
        Qs[(cv + 0) * 64 + r] = v.x;
        Qs[(cv + 1) * 64 + r] = v.y;
        Qs[(cv + 2) * 64 + r] = v.z;
        Qs[(cv + 3) * 64 + r] = v.w;
    }

    float mrow[4], lrow[4], ctx[4][4];
#pragma unroll
    for (int i = 0; i < 4; ++i) {
        mrow[i] = -1e30f;
        lrow[i] = 0.f;
#pragma unroll
        for (int j = 0; j < 4; ++j) ctx[i][j] = 0.f;
    }

    for (int kt = 0; kt < SEQ / 64; ++kt) {
        const float* Kbase = K + (size_t)(b * SEQ + kt * 64) * DIM + h * DPH;
        const float* Vbase = V + (size_t)(b * SEQ + kt * 64) * DIM + h * DPH;
        __syncthreads();  // previous iteration's PV reads done before overwrite
#pragma unroll
        for (int i = 0; i < 4; ++i) {
            int idx = i * 256 + tid;
            int r = idx >> 4, cv = (idx & 15) << 2;
            float4 kv = *(const float4*)&Kbase[(size_t)r * DIM + cv];
            float4 vv = *(const float4*)&Vbase[(size_t)r * DIM + cv];
            Ks[(cv + 0) * 64 + r] = kv.x;
            Ks[(cv + 1) * 64 + r] = kv.y;
            Ks[(cv + 2) * 64 + r] = kv.z;
            Ks[(cv + 3) * 64 + r] = kv.w;
            *(float4*)&Vs[r * DPH + cv] = vv;
        }
        __syncthreads();

        // S = Q K^T  (4x4 per thread)
        float S[4][4];
#pragma unroll
        for (int i = 0; i < 4; ++i)
#pragma unroll
            for (int j = 0; j < 4; ++j) S[i][j] = 0.f;

#pragma unroll 8
        for (int d = 0; d < DPH; ++d) {
            float4 qv = *(const float4*)&Qs[d * 64 + rq * 4];
            float4 kv = *(const float4*)&Ks[d * 64 + cq * 4];
            float qa[4] = {qv.x, qv.y, qv.z, qv.w};
            float ka[4] = {kv.x, kv.y, kv.z, kv.w};
#pragma unroll
            for (int i = 0; i < 4; ++i)
#pragma unroll
                for (int j = 0; j < 4; ++j)
                    S[i][j] = fmaf(qa[i], ka[j], S[i][j]);
        }

        // mask (per key column)
        const int* mb = mask + b * SEQ + kt * 64 + cq * 4;
        int mkv[4] = {mb[0], mb[1], mb[2], mb[3]};
#pragma unroll
        for (int j = 0; j < 4; ++j)
            if (mkv[j] == 0) {
#pragma unroll
                for (int i = 0; i < 4; ++i) S[i][j] = -1e30f;
            }

        // online softmax (rows split across 16 lanes: shfl width 16)
#pragma unroll
        for (int i = 0; i < 4; ++i) {
            float t = fmaxf(fmaxf(S[i][0], S[i][1]), fmaxf(S[i][2], S[i][3]));
            t = fmaxf(t, __shfl_xor(t, 1));
            t = fmaxf(t, __shfl_xor(t, 2));
            t = fmaxf(t, __shfl_xor(t, 4));
            t = fmaxf(t, __shfl_xor(t, 8));
            float mn = fmaxf(mrow[i], t);
            float alpha = __expf(mrow[i] - mn);
            float4 p;
            p.x = __expf(S[i][0] - mn);
            p.y = __expf(S[i][1] - mn);
            p.z = __expf(S[i][2] - mn);
            p.w = __expf(S[i][3] - mn);
            float ps = p.x + p.y + p.z + p.w;
            ps += __shfl_xor(ps, 1);
            ps += __shfl_xor(ps, 2);
            ps += __shfl_xor(ps, 4);
            ps += __shfl_xor(ps, 8);
            lrow[i] = lrow[i] * alpha + ps;
            mrow[i] = mn;
            *(float4*)&Ps[(rq * 4 + i) * PSS + cq * 4] = p;
#pragma unroll
            for (int j = 0; j < 4; ++j) ctx[i][j] *= alpha;
        }
        __syncthreads();

        // ctx += P @ V  (4x4 per thread)
#pragma unroll 4
        for (int j4 = 0; j4 < 16; ++j4) {
            float4 p0 = *(const float4*)&Ps[(rq * 4 + 0) * PSS + j4 * 4];
            float4 p1 = *(const float4*)&Ps[(rq * 4 + 1) * PSS + j4 * 4];
            float4 p2 = *(const float4*)&Ps[(rq * 4 + 2) * PSS + j4 * 4];
            float4 p3 = *(const float4*)&Ps[(rq * 4 + 3) * PSS + j4 * 4];
            float4 v0 = *(const float4*)&Vs[(j4 * 4 + 0) * DPH + cq * 4];
            float4 v1 = *(const float4*)&Vs[(j4 * 4 + 1) * DPH + cq * 4];
            float4 v2 = *(const float4*)&Vs[(j4 * 4 + 2) * DPH + cq * 4];
            float4 v3 = *(const float4*)&Vs[(j4 * 4 + 3) * DPH + cq * 4];
            float pa[4][4] = {{p0.x, p0.y, p0.z, p0.w},
                              {p1.x, p1.y, p1.z, p1.w},
                              {p2.x, p2.y, p2.z, p2.w},
                              {p3.x, p3.y, p3.z, p3.w}};
            float va[4][4] = {{v0.x, v0.y, v0.z, v0.w},
                              {v1.x, v1.y, v1.z, v1.w},
                              {v2.x, v2.y, v2.z, v2.w},
                              {v3.x, v3.y, v3.z, v3.w}};
#pragma unroll
            for (int i = 0; i < 4; ++i)
#pragma unroll
                for (int jj = 0; jj < 4; ++jj)
#pragma unroll
                    for (int dc = 0; dc < 4; ++dc)
                        ctx[i][dc] = fmaf(pa[i][jj], va[jj][dc], ctx[i][dc]);
        }
    }

    float* Cb = CTX + (size_t)(b * SEQ + qt * 64) * DIM + h * DPH;
#pragma unroll
    for (int i = 0; i < 4; ++i) {
        float inv = 1.0f / lrow[i];
        float4 o = {ctx[i][0] * inv, ctx[i][1] * inv, ctx[i][2] * inv, ctx[i][3] * inv};
        *(float4*)&Cb[(size_t)(rq * 4 + i) * DIM + cq * 4] = o;
    }
}

// ---------------- launch ----------------
extern "C" void kernel_launch(void* const* d_in, const int* in_sizes, int n_in,
                              void* d_out, int out_size, void* d_ws, size_t ws_size,
                              hipStream_t stream)
{
    const float* x    = (const float*)d_in[0];
    const int*   mask = (const int*)d_in[1];
    const float* Wq   = (const float*)d_in[2];
    const float* bq   = (const float*)d_in[3];
    const float* Wk   = (const float*)d_in[4];
    const float* bk   = (const float*)d_in[5];
    const float* Wv   = (const float*)d_in[6];
    const float* bv   = (const float*)d_in[7];
    const float* Wo   = (const float*)d_in[8];
    const float* bo   = (const float*)d_in[9];
    const float* scale = (const float*)d_in[10];
    float* out = (float*)d_out;

    float* ws  = (float*)d_ws;
    float* Q   = ws;                          // 4096*1024 f32 = 16 MB
    float* K   = Q + (size_t)MTOT * DIM;      // 16 MB
    float* V   = K + (size_t)MTOT * DIM;      // 16 MB
    float* CTX = V + (size_t)MTOT * DIM;      // 16 MB

    qkv_gemm<<<dim3(DIM / BNN, MTOT / BMM, 3), 256, 0, stream>>>(
        x, Wq, bq, Wk, bk, Wv, bv, Q, K, V);
    norm_qk<<<dim3(MTOT * NH / 4), 256, 0, stream>>>(Q, K, scale);
    attn<<<dim3(SEQ / 64, NH, BS2), 256, 0, stream>>>(Q, K, V, mask, CTX);
    o_gemm<<<dim3(DIM / BNN, MTOT / BMM, 1), 256, 0, stream>>>(CTX, Wo, bo, out);
}

// Round 2
// 317.230 us; speedup vs baseline: 3.6666x; 3.6666x over previous
//
#include <hip/hip_runtime.h>
#include <math.h>

#define SEQ 2048
#define DIM 1024
#define NH 16
#define DPH 64
#define MTOT 4096  // BS2 * SEQ

typedef __attribute__((ext_vector_type(8))) short bf16x8;
typedef __attribute__((ext_vector_type(4))) float f32x4;

__device__ __forceinline__ unsigned short f2bf(float f) {
    unsigned int u = __float_as_uint(f);
    return (unsigned short)((u + 0x7FFFu + ((u >> 16) & 1u)) >> 16);
}
__device__ __forceinline__ float bf2f(unsigned short h) {
    return __uint_as_float(((unsigned int)h) << 16);
}

// async global->LDS, 16B per lane; dest = uniform base + lane*16 (HW rule)
__device__ __forceinline__ void stage16(const void* g, void* lds) {
    __builtin_amdgcn_global_load_lds((const __attribute__((address_space(1))) void*)g,
                                     (__attribute__((address_space(3))) void*)lds,
                                     16, 0, 0);
}

// ---------------- prep: cast x to bf16 ----------------
__global__ __launch_bounds__(256) void cast_x(const float* __restrict__ X,
                                              unsigned short* __restrict__ Xb)
{
    size_t i = (size_t)blockIdx.x * 256 + threadIdx.x;
    float4 v = *(const float4*)&X[i * 4];
    ushort4 o;
    o.x = f2bf(v.x); o.y = f2bf(v.y); o.z = f2bf(v.z); o.w = f2bf(v.w);
    *(ushort4*)&Xb[i * 4] = o;
}

// ---------------- prep: transpose-cast W [k][n] f32 -> Wt [n][k] bf16 ----------------
__global__ __launch_bounds__(256) void prep_w(
    const float* __restrict__ Wq, const float* __restrict__ Wk,
    const float* __restrict__ Wv, const float* __restrict__ Wo,
    unsigned short* __restrict__ Wqt, unsigned short* __restrict__ Wkt,
    unsigned short* __restrict__ Wvt, unsigned short* __restrict__ Wot)
{
    const float* W; unsigned short* Wt;
    switch (blockIdx.z) {
        case 0: W = Wq; Wt = Wqt; break;
        case 1: W = Wk; Wt = Wkt; break;
        case 2: W = Wv; Wt = Wvt; break;
        default: W = Wo; Wt = Wot; break;
    }
    __shared__ float T[32][33];
    const int t = threadIdx.x;
    const int kt0 = blockIdx.y * 32;
    const int nt0 = blockIdx.x * 32;
    const int r = t >> 3, c4 = (t & 7) * 4;
    float4 v = *(const float4*)&W[(size_t)(kt0 + r) * DIM + nt0 + c4];
    T[r][c4 + 0] = v.x; T[r][c4 + 1] = v.y; T[r][c4 + 2] = v.z; T[r][c4 + 3] = v.w;
    __syncthreads();
    ushort4 o;
    o.x = f2bf(T[c4 + 0][r]);
    o.y = f2bf(T[c4 + 1][r]);
    o.z = f2bf(T[c4 + 2][r]);
    o.w = f2bf(T[c4 + 3][r]);
    *(ushort4*)&Wt[(size_t)(nt0 + r) * DIM + kt0 + c4] = o;
}

// ---------------- bf16 MFMA GEMM core: C[M,1024] = A[M,1024] @ Bt[N,1024]^T + bias ----------------
// 128x128 tile, BK=32, 4 waves (wave = 64x64 quadrant), fragment-major LDS,
// staged by global_load_lds w=16 (linear dest, per-lane source).
// mode 0: bf16 row-major out; mode 1: bf16 transposed V out [b,h,d,seq]; mode 2: fp32 out.
__device__ __forceinline__ void gemm_core(
    const unsigned short* __restrict__ Ab, const unsigned short* __restrict__ Bt,
    const float* __restrict__ bias, unsigned short* __restrict__ Cb,
    float* __restrict__ Cf, int mode)
{
    __shared__ __align__(16) unsigned short As[4096];  // 8 subtiles x [kg4][row16][8]
    __shared__ __align__(16) unsigned short Bs[4096];

    const int tid = threadIdx.x;
    const int l = tid & 63;
    const int w = tid >> 6;
    const int wm = w >> 1, wn = w & 1;
    const int lr = l & 15, lg = l >> 4;
    const int bm = blockIdx.y * 128;
    const int bn = blockIdx.x * 128;

    const unsigned short* a_src0 = Ab + (size_t)(bm + (2 * w) * 16 + lr) * DIM + lg * 8;
    const unsigned short* a_src1 = Ab + (size_t)(bm + (2 * w + 1) * 16 + lr) * DIM + lg * 8;
    const unsigned short* b_src0 = Bt + (size_t)(bn + (2 * w) * 16 + lr) * DIM + lg * 8;
    const unsigned short* b_src1 = Bt + (size_t)(bn + (2 * w + 1) * 16 + lr) * DIM + lg * 8;

    f32x4 acc[4][4];
#pragma unroll
    for (int i = 0; i < 4; ++i)
#pragma unroll
        for (int j = 0; j < 4; ++j) acc[i][j] = (f32x4){0.f, 0.f, 0.f, 0.f};

    for (int kk = 0; kk < DIM; kk += 32) {
        __syncthreads();
        stage16(a_src0 + kk, &As[(2 * w) * 512]);
        stage16(a_src1 + kk, &As[(2 * w + 1) * 512]);
        stage16(b_src0 + kk, &Bs[(2 * w) * 512]);
        stage16(b_src1 + kk, &Bs[(2 * w + 1) * 512]);
        __syncthreads();

        bf16x8 aF[4], bF[4];
#pragma unroll
        for (int i = 0; i < 4; ++i) {
            aF[i] = *(const bf16x8*)&As[(wm * 4 + i) * 512 + l * 8];
            bF[i] = *(const bf16x8*)&Bs[(wn * 4 + i) * 512 + l * 8];
        }
#pragma unroll
        for (int i = 0; i < 4; ++i)
#pragma unroll
            for (int j = 0; j < 4; ++j)
                acc[i][j] = __builtin_amdgcn_mfma_f32_16x16x32_bf16(aF[i], bF[j], acc[i][j], 0, 0, 0);
    }

#pragma unroll
    for (int i = 0; i < 4; ++i) {
#pragma unroll
        for (int j = 0; j < 4; ++j) {
            const int n = bn + wn * 64 + j * 16 + lr;
            const float bv = bias[n];
            const int m0 = bm + wm * 64 + i * 16 + lg * 4;
            if (mode == 0) {
#pragma unroll
                for (int p = 0; p < 4; ++p)
                    Cb[(size_t)(m0 + p) * DIM + n] = f2bf(acc[i][j][p] + bv);
            } else if (mode == 1) {
                const int b = m0 >> 11, s = m0 & 2047;
                const int h = n >> 6, d = n & 63;
                ushort4 o;
                o.x = f2bf(acc[i][j][0] + bv);
                o.y = f2bf(acc[i][j][1] + bv);
                o.z = f2bf(acc[i][j][2] + bv);
                o.w = f2bf(acc[i][j][3] + bv);
                *(ushort4*)&Cb[((size_t)((b * NH + h) * DPH + d)) * SEQ + s] = o;
            } else {
#pragma unroll
                for (int p = 0; p < 4; ++p)
                    Cf[(size_t)(m0 + p) * DIM + n] = acc[i][j][p] + bv;
            }
        }
    }
}

__global__ __launch_bounds__(256) void qkv_gemm(
    const unsigned short* __restrict__ Xb,
    const unsigned short* __restrict__ Wqt, const unsigned short* __restrict__ Wkt,
    const unsigned short* __restrict__ Wvt,
    const float* __restrict__ bq, const float* __restrict__ bk, const float* __restrict__ bv,
    unsigned short* __restrict__ Qb, unsigned short* __restrict__ Kb,
    unsigned short* __restrict__ Vtb)
{
    if (blockIdx.z == 0)      gemm_core(Xb, Wqt, bq, Qb,  nullptr, 0);
    else if (blockIdx.z == 1) gemm_core(Xb, Wkt, bk, Kb,  nullptr, 0);
    else                      gemm_core(Xb, Wvt, bv, Vtb, nullptr, 1);
}

__global__ __launch_bounds__(256) void o_gemm(
    const unsigned short* __restrict__ Ab, const unsigned short* __restrict__ Wot,
    const float* __restrict__ bo, float* __restrict__ Out)
{
    gemm_core(Ab, Wot, bo, nullptr, Out, 2);
}

// ---------------- L2-normalize q (x scale) and k per (row, head), bf16 in/out ----------------
__global__ __launch_bounds__(256) void norm_qk(
    unsigned short* __restrict__ Qb, unsigned short* __restrict__ Kb,
    const float* __restrict__ scale_p)
{
    const int row = blockIdx.x;
    const int tid = threadIdx.x;
    unsigned short* buf = (tid < 128) ? Qb : Kb;
    const int g = tid & 127;                 // 8 lanes per head (8 elems each)
    const size_t base = (size_t)row * DIM + g * 8;
    ushort4 v0 = *(ushort4*)&buf[base];
    ushort4 v1 = *(ushort4*)&buf[base + 4];
    float f[8] = {bf2f(v0.x), bf2f(v0.y), bf2f(v0.z), bf2f(v0.w),
                  bf2f(v1.x), bf2f(v1.y), bf2f(v1.z), bf2f(v1.w)};
    float s = 0.f;
#pragma unroll
    for (int i = 0; i < 8; ++i) s = fmaf(f[i], f[i], s);
    s += __shfl_xor(s, 1);
    s += __shfl_xor(s, 2);
    s += __shfl_xor(s, 4);
    const float scl = ((tid < 128) ? *scale_p : 1.0f) / fmaxf(sqrtf(s), 1e-12f);
    ushort4 o0, o1;
    o0.x = f2bf(f[0] * scl); o0.y = f2bf(f[1] * scl);
    o0.z = f2bf(f[2] * scl); o0.w = f2bf(f[3] * scl);
    o1.x = f2bf(f[4] * scl); o1.y = f2bf(f[5] * scl);
    o1.z = f2bf(f[6] * scl); o1.w = f2bf(f[7] * scl);
    *(ushort4*)&buf[base] = o0;
    *(ushort4*)&buf[base + 4] = o1;
}

// ---------------- flash attention, bf16 MFMA ----------------
// block: 64 q-rows, 4 waves x 16 rows; K-tile 64x64 + Vt-tile 64x64 in LDS (XOR-swizzled),
// per-wave P tile 16x64 (XOR-swizzled) for the QK^T->PV layout change.
__global__ __launch_bounds__(256) void attn(
    const unsigned short* __restrict__ Qb, const unsigned short* __restrict__ Kb,
    const unsigned short* __restrict__ Vtb, const int* __restrict__ mask,
    unsigned short* __restrict__ CTXb)
{
    __shared__ __align__(16) unsigned short Ks[4096];   // [key64][d64] swizzled
    __shared__ __align__(16) unsigned short Vts[4096];  // [d64][key64] swizzled
    __shared__ __align__(16) unsigned short Ps[4096];   // 4 waves x [q16][key64] swizzled

    const int tid = threadIdx.x;
    const int l = tid & 63;
    const int w = tid >> 6;
    const int lr = l & 15, lg = l >> 4;
    const int qt = blockIdx.x, h = blockIdx.y, b = blockIdx.z;

    const size_t qrow0 = (size_t)(b * SEQ + qt * 64 + w * 16);
    bf16x8 qf[2];
    qf[0] = *(const bf16x8*)&Qb[(qrow0 + lr) * DIM + h * DPH + lg * 8];
    qf[1] = *(const bf16x8*)&Qb[(qrow0 + lr) * DIM + h * DPH + 32 + lg * 8];

    // staging lane mapping: row-in-8 = l>>3, logical slot = (l&7) ^ (row&7) (pre-swizzled source)
    const int srow = l >> 3;
    const int sslot = (l & 7) ^ srow;
    const unsigned short* Kbase = Kb + (size_t)(b * SEQ) * DIM + h * DPH;
    const unsigned short* Vbase = Vtb + ((size_t)(b * NH + h) * DPH) * SEQ;

    f32x4 ctx[4];
    float mx[4], lsum[4];
#pragma unroll
    for (int i = 0; i < 4; ++i) { ctx[i] = (f32x4){0.f, 0.f, 0.f, 0.f}; mx[i] = -1e30f; lsum[i] = 0.f; }

    char* pbase = (char*)&Ps[w * 1024];

    for (int kt = 0; kt < SEQ / 64; ++kt) {
        __syncthreads();
        {
            const int i0 = 2 * w, i1 = 2 * w + 1;
            stage16(Kbase + (size_t)(kt * 64 + i0 * 8 + srow) * DIM + sslot * 8, &Ks[i0 * 512]);
            stage16(Kbase + (size_t)(kt * 64 + i1 * 8 + srow) * DIM + sslot * 8, &Ks[i1 * 512]);
            stage16(Vbase + (size_t)(i0 * 8 + srow) * SEQ + kt * 64 + sslot * 8, &Vts[i0 * 512]);
            stage16(Vbase + (size_t)(i1 * 8 + srow) * SEQ + kt * 64 + sslot * 8, &Vts[i1 * 512]);
        }
        __syncthreads();

        // S = Q K^T : 4 key-frags x 2 d-halves
        f32x4 S[4];
#pragma unroll
        for (int nj = 0; nj < 4; ++nj) S[nj] = (f32x4){0.f, 0.f, 0.f, 0.f};
#pragma unroll
        for (int nj = 0; nj < 4; ++nj) {
            const int row = nj * 16 + lr;
#pragma unroll
            for (int dh = 0; dh < 2; ++dh) {
                const int slot = dh * 4 + lg;
                bf16x8 kf = *(const bf16x8*)((const char*)Ks + row * 128 + ((slot ^ (row & 7)) << 4));
                S[nj] = __builtin_amdgcn_mfma_f32_16x16x32_bf16(qf[dh], kf, S[nj], 0, 0, 0);
            }
        }

        // mask (column = key)
        const int* mrow = mask + b * SEQ + kt * 64;
#pragma unroll
        for (int nj = 0; nj < 4; ++nj) {
            if (mrow[nj * 16 + lr] == 0) {
                S[nj][0] = -1e30f; S[nj][1] = -1e30f; S[nj][2] = -1e30f; S[nj][3] = -1e30f;
            }
        }

        // online softmax per owned q-row (p)
        float alpha[4];
#pragma unroll
        for (int p = 0; p < 4; ++p) {
            float t = fmaxf(fmaxf(S[0][p], S[1][p]), fmaxf(S[2][p], S[3][p]));
            t = fmaxf(t, __shfl_xor(t, 1));
            t = fmaxf(t, __shfl_xor(t, 2));
            t = fmaxf(t, __shfl_xor(t, 4));
            t = fmaxf(t, __shfl_xor(t, 8));
            const float mn = fmaxf(mx[p], t);
            alpha[p] = __expf(mx[p] - mn);
            mx[p] = mn;
            float rs = 0.f;
            const int r = lg * 4 + p;
#pragma unroll
            for (int nj = 0; nj < 4; ++nj) {
                const float pv = __expf(S[nj][p] - mn);
                rs += pv;
                const int c = nj * 16 + lr;
                *(unsigned short*)(pbase + r * 128 + ((((c >> 3) ^ (r & 7)) << 4) | ((c & 7) * 2))) = f2bf(pv);
            }
            rs += __shfl_xor(rs, 1);
            rs += __shfl_xor(rs, 2);
            rs += __shfl_xor(rs, 4);
            rs += __shfl_xor(rs, 8);
            lsum[p] = lsum[p] * alpha[p] + rs;
        }
#pragma unroll
        for (int dj = 0; dj < 4; ++dj)
#pragma unroll
            for (int p = 0; p < 4; ++p) ctx[dj][p] *= alpha[p];

        // ctx += P @ V : A-frags from per-wave P, B-frags from swizzled Vt
        bf16x8 pa[2];
#pragma unroll
        for (int kh = 0; kh < 2; ++kh) {
            const int blk = kh * 4 + lg;
            pa[kh] = *(const bf16x8*)(pbase + lr * 128 + ((blk ^ (lr & 7)) << 4));
        }
#pragma unroll
        for (int dj = 0; dj < 4; ++dj) {
            const int d = dj * 16 + lr;
#pragma unroll
            for (int kh = 0; kh < 2; ++kh) {
                const int slot = kh * 4 + lg;
                bf16x8 vb = *(const bf16x8*)((const char*)Vts + d * 128 + ((slot ^ (d & 7)) << 4));
                ctx[dj] = __builtin_amdgcn_mfma_f32_16x16x32_bf16(pa[kh], vb, ctx[dj], 0, 0, 0);
            }
        }
    }

    // epilogue: ctx / l -> bf16 CTX rows
#pragma unroll
    for (int p = 0; p < 4; ++p) {
        const float inv = 1.0f / lsum[p];
        const size_t row = qrow0 + lg * 4 + p;
#pragma unroll
        for (int dj = 0; dj < 4; ++dj)
            CTXb[row * DIM + h * DPH + dj * 16 + lr] = f2bf(ctx[dj][p] * inv);
    }
}

// ---------------- launch ----------------
extern "C" void kernel_launch(void* const* d_in, const int* in_sizes, int n_in,
                              void* d_out, int out_size, void* d_ws, size_t ws_size,
                              hipStream_t stream)
{
    const float* x    = (const float*)d_in[0];
    const int*   mask = (const int*)d_in[1];
    const float* Wq   = (const float*)d_in[2];
    const float* bq   = (const float*)d_in[3];
    const float* Wk   = (const float*)d_in[4];
    const float* bk   = (const float*)d_in[5];
    const float* Wv   = (const float*)d_in[6];
    const float* bv   = (const float*)d_in[7];
    const float* Wo   = (const float*)d_in[8];
    const float* bo   = (const float*)d_in[9];
    const float* scale = (const float*)d_in[10];
    float* out = (float*)d_out;

    char* p = (char*)d_ws;
    unsigned short* Xb  = (unsigned short*)p; p += (size_t)MTOT * DIM * 2;  // 8 MB
    unsigned short* Wqt = (unsigned short*)p; p += (size_t)DIM * DIM * 2;   // 2 MB
    unsigned short* Wkt = (unsigned short*)p; p += (size_t)DIM * DIM * 2;
    unsigned short* Wvt = (unsigned short*)p; p += (size_t)DIM * DIM * 2;
    unsigned short* Wot = (unsigned short*)p; p += (size_t)DIM * DIM * 2;
    unsigned short* Qb  = (unsigned short*)p; p += (size_t)MTOT * DIM * 2;  // 8 MB
    unsigned short* Kb  = (unsigned short*)p; p += (size_t)MTOT * DIM * 2;
    unsigned short* Vtb = (unsigned short*)p; p += (size_t)MTOT * DIM * 2;  // [b,h,d,seq]
    unsigned short* CTXb = (unsigned short*)p;                               // 8 MB

    cast_x<<<dim3(MTOT * DIM / 4 / 256), 256, 0, stream>>>(x, Xb);
    prep_w<<<dim3(32, 32, 4), 256, 0, stream>>>(Wq, Wk, Wv, Wo, Wqt, Wkt, Wvt, Wot);
    qkv_gemm<<<dim3(DIM / 128, MTOT / 128, 3), 256, 0, stream>>>(
        Xb, Wqt, Wkt, Wvt, bq, bk, bv, Qb, Kb, Vtb);
    norm_qk<<<dim3(MTOT), 256, 0, stream>>>(Qb, Kb, scale);
    attn<<<dim3(SEQ / 64, NH, 2), 256, 0, stream>>>(Qb, Kb, Vtb, mask, CTXb);
    o_gemm<<<dim3(DIM / 128, MTOT / 128, 1), 256, 0, stream>>>(CTXb, Wot, bo, out);
}

// Round 4
// 254.904 us; speedup vs baseline: 4.5631x; 1.2445x over previous
//
#include <hip/hip_runtime.h>
#include <math.h>

#define SEQ 2048
#define DIM 1024
#define NH 16
#define DPH 64
#define MTOT 4096  // BS2 * SEQ

typedef __attribute__((ext_vector_type(8))) short bf16x8;
typedef __attribute__((ext_vector_type(4))) float f32x4;
typedef __attribute__((ext_vector_type(16))) float f32x16;
typedef __attribute__((ext_vector_type(4))) unsigned int u32x4;

__device__ __forceinline__ unsigned short f2bf(float f) {
    unsigned int u = __float_as_uint(f);
    return (unsigned short)((u + 0x7FFFu + ((u >> 16) & 1u)) >> 16);
}
__device__ __forceinline__ float bf2f(unsigned short h) {
    return __uint_as_float(((unsigned int)h) << 16);
}

__device__ __forceinline__ void stage16(const void* g, void* lds) {
    __builtin_amdgcn_global_load_lds((const __attribute__((address_space(1))) void*)g,
                                     (__attribute__((address_space(3))) void*)lds,
                                     16, 0, 0);
}

__device__ __forceinline__ unsigned cvtpk(float lo, float hi) {
    unsigned w;
    asm("v_cvt_pk_bf16_f32 %0, %1, %2" : "=v"(w) : "v"(lo), "v"(hi));
    return w;
}
// v_permlane32_swap_b32 A, B:  A' = {A_lo, B_lo}, B' = {A_hi, B_hi}
__device__ __forceinline__ void plswap(unsigned &a, unsigned &b) {
    asm("v_permlane32_swap_b32 %0, %1" : "+v"(a), "+v"(b));
}

// ---------------- prep: cast x to bf16 ----------------
__global__ __launch_bounds__(256) void cast_x(const float* __restrict__ X,
                                              unsigned short* __restrict__ Xb)
{
    size_t i = (size_t)blockIdx.x * 256 + threadIdx.x;
    float4 v = *(const float4*)&X[i * 4];
    ushort4 o;
    o.x = f2bf(v.x); o.y = f2bf(v.y); o.z = f2bf(v.z); o.w = f2bf(v.w);
    *(ushort4*)&Xb[i * 4] = o;
}

// ---------------- prep: transpose-cast W [k][n] f32 -> Wt [n][k] bf16 ----------------
__global__ __launch_bounds__(256) void prep_w(
    const float* __restrict__ Wq, const float* __restrict__ Wk,
    const float* __restrict__ Wv, const float* __restrict__ Wo,
    unsigned short* __restrict__ Wqt, unsigned short* __restrict__ Wkt,
    unsigned short* __restrict__ Wvt, unsigned short* __restrict__ Wot)
{
    const float* W; unsigned short* Wt;
    switch (blockIdx.z) {
        case 0: W = Wq; Wt = Wqt; break;
        case 1: W = Wk; Wt = Wkt; break;
        case 2: W = Wv; Wt = Wvt; break;
        default: W = Wo; Wt = Wot; break;
    }
    __shared__ float T[32][33];
    const int t = threadIdx.x;
    const int kt0 = blockIdx.y * 32;
    const int nt0 = blockIdx.x * 32;
    const int r = t >> 3, c4 = (t & 7) * 4;
    float4 v = *(const float4*)&W[(size_t)(kt0 + r) * DIM + nt0 + c4];
    T[r][c4 + 0] = v.x; T[r][c4 + 1] = v.y; T[r][c4 + 2] = v.z; T[r][c4 + 3] = v.w;
    __syncthreads();
    ushort4 o;
    o.x = f2bf(T[c4 + 0][r]);
    o.y = f2bf(T[c4 + 1][r]);
    o.z = f2bf(T[c4 + 2][r]);
    o.w = f2bf(T[c4 + 3][r]);
    *(ushort4*)&Wt[(size_t)(nt0 + r) * DIM + kt0 + c4] = o;
}

// ---------------- pack mask bits: maskbits[b][kt] = 64-bit word over keys ----------------
__global__ __launch_bounds__(256) void pack_mask(const int* __restrict__ mask,
                                                 unsigned long long* __restrict__ MB)
{
    const int w = blockIdx.x * 4 + (threadIdx.x >> 6);  // word 0..63
    const int lane = threadIdx.x & 63;
    const int b = w >> 5, kt = w & 31;
    int m = mask[b * SEQ + kt * 64 + lane];
    unsigned long long bits = __ballot(m != 0);
    if (lane == 0) MB[w] = bits;
}

// ---------------- bf16 MFMA GEMM core (m97-style): C = A @ Bt^T + bias ----------------
__device__ __forceinline__ void gemm_core(
    const unsigned short* __restrict__ Ab, const unsigned short* __restrict__ Bt,
    const float* __restrict__ bias, unsigned short* __restrict__ Cb,
    float* __restrict__ Cf, int mode)
{
    __shared__ __align__(16) unsigned short As[4096];
    __shared__ __align__(16) unsigned short Bs[4096];

    const int tid = threadIdx.x;
    const int l = tid & 63;
    const int w = tid >> 6;
    const int wm = w >> 1, wn = w & 1;
    const int lr = l & 15, lg = l >> 4;
    const int bm = blockIdx.y * 128;
    const int bn = blockIdx.x * 128;

    const unsigned short* a_src0 = Ab + (size_t)(bm + (2 * w) * 16 + lr) * DIM + lg * 8;
    const unsigned short* a_src1 = Ab + (size_t)(bm + (2 * w + 1) * 16 + lr) * DIM + lg * 8;
    const unsigned short* b_src0 = Bt + (size_t)(bn + (2 * w) * 16 + lr) * DIM + lg * 8;
    const unsigned short* b_src1 = Bt + (size_t)(bn + (2 * w + 1) * 16 + lr) * DIM + lg * 8;

    f32x4 acc[4][4];
#pragma unroll
    for (int i = 0; i < 4; ++i)
#pragma unroll
        for (int j = 0; j < 4; ++j) acc[i][j] = (f32x4){0.f, 0.f, 0.f, 0.f};

    for (int kk = 0; kk < DIM; kk += 32) {
        __syncthreads();
        stage16(a_src0 + kk, &As[(2 * w) * 512]);
        stage16(a_src1 + kk, &As[(2 * w + 1) * 512]);
        stage16(b_src0 + kk, &Bs[(2 * w) * 512]);
        stage16(b_src1 + kk, &Bs[(2 * w + 1) * 512]);
        __syncthreads();

        bf16x8 aF[4], bF[4];
#pragma unroll
        for (int i = 0; i < 4; ++i) {
            aF[i] = *(const bf16x8*)&As[(wm * 4 + i) * 512 + l * 8];
            bF[i] = *(const bf16x8*)&Bs[(wn * 4 + i) * 512 + l * 8];
        }
#pragma unroll
        for (int i = 0; i < 4; ++i)
#pragma unroll
            for (int j = 0; j < 4; ++j)
                acc[i][j] = __builtin_amdgcn_mfma_f32_16x16x32_bf16(aF[i], bF[j], acc[i][j], 0, 0, 0);
    }

#pragma unroll
    for (int i = 0; i < 4; ++i) {
#pragma unroll
        for (int j = 0; j < 4; ++j) {
            const int n = bn + wn * 64 + j * 16 + lr;
            const float bv = bias[n];
            const int m0 = bm + wm * 64 + i * 16 + lg * 4;
            if (mode == 0) {
#pragma unroll
                for (int p = 0; p < 4; ++p)
                    Cb[(size_t)(m0 + p) * DIM + n] = f2bf(acc[i][j][p] + bv);
            } else if (mode == 1) {
                const int b = m0 >> 11, s = m0 & 2047;
                const int h = n >> 6, d = n & 63;
                ushort4 o;
                o.x = f2bf(acc[i][j][0] + bv);
                o.y = f2bf(acc[i][j][1] + bv);
                o.z = f2bf(acc[i][j][2] + bv);
                o.w = f2bf(acc[i][j][3] + bv);
                *(ushort4*)&Cb[((size_t)((b * NH + h) * DPH + d)) * SEQ + s] = o;
            } else {
#pragma unroll
                for (int p = 0; p < 4; ++p)
                    Cf[(size_t)(m0 + p) * DIM + n] = acc[i][j][p] + bv;
            }
        }
    }
}

__global__ __launch_bounds__(256) void qkv_gemm(
    const unsigned short* __restrict__ Xb,
    const unsigned short* __restrict__ Wqt, const unsigned short* __restrict__ Wkt,
    const unsigned short* __restrict__ Wvt,
    const float* __restrict__ bq, const float* __restrict__ bk, const float* __restrict__ bv,
    unsigned short* __restrict__ Qb, unsigned short* __restrict__ Kb,
    unsigned short* __restrict__ Vtb)
{
    if (blockIdx.z == 0)      gemm_core(Xb, Wqt, bq, Qb,  nullptr, 0);
    else if (blockIdx.z == 1) gemm_core(Xb, Wkt, bk, Kb,  nullptr, 0);
    else                      gemm_core(Xb, Wvt, bv, Vtb, nullptr, 1);
}

__global__ __launch_bounds__(256) void o_gemm(
    const unsigned short* __restrict__ Ab, const unsigned short* __restrict__ Wot,
    const float* __restrict__ bo, float* __restrict__ Out)
{
    gemm_core(Ab, Wot, bo, nullptr, Out, 2);
}

// ---------------- L2-normalize q (x scale x log2e) and k, bf16 in/out ----------------
__global__ __launch_bounds__(256) void norm_qk(
    unsigned short* __restrict__ Qb, unsigned short* __restrict__ Kb,
    const float* __restrict__ scale_p)
{
    const int row = blockIdx.x;
    const int tid = threadIdx.x;
    unsigned short* buf = (tid < 128) ? Qb : Kb;
    const int g = tid & 127;
    const size_t base = (size_t)row * DIM + g * 8;
    ushort4 v0 = *(ushort4*)&buf[base];
    ushort4 v1 = *(ushort4*)&buf[base + 4];
    float f[8] = {bf2f(v0.x), bf2f(v0.y), bf2f(v0.z), bf2f(v0.w),
                  bf2f(v1.x), bf2f(v1.y), bf2f(v1.z), bf2f(v1.w)};
    float s = 0.f;
#pragma unroll
    for (int i = 0; i < 8; ++i) s = fmaf(f[i], f[i], s);
    s += __shfl_xor(s, 1);
    s += __shfl_xor(s, 2);
    s += __shfl_xor(s, 4);
    // q gets scale * log2(e) folded in: attn uses exp2 directly
    const float scl = ((tid < 128) ? (*scale_p * 1.44269504088896340736f) : 1.0f)
                      / fmaxf(sqrtf(s), 1e-12f);
    ushort4 o0, o1;
    o0.x = f2bf(f[0] * scl); o0.y = f2bf(f[1] * scl);
    o0.z = f2bf(f[2] * scl); o0.w = f2bf(f[3] * scl);
    o1.x = f2bf(f[4] * scl); o1.y = f2bf(f[5] * scl);
    o1.z = f2bf(f[6] * scl); o1.w = f2bf(f[7] * scl);
    *(ushort4*)&buf[base] = o0;
    *(ushort4*)&buf[base + 4] = o1;
}

// ---------------- flash attention, 32x32x16 MFMA, swapped QK^T, no-max softmax ----------------
// Block: 4 waves x 32 q-rows = 128 q-rows. KVBLK=64. K,Vt double-buffered LDS (XOR swizzled).
// Cosine attention: |S| <= ~0.13 -> P = exp2(S) directly, no max tracking, no rescale.
__global__ __launch_bounds__(256) void attn(
    const unsigned short* __restrict__ Qb, const unsigned short* __restrict__ Kb,
    const unsigned short* __restrict__ Vtb, const unsigned long long* __restrict__ MB,
    unsigned short* __restrict__ CTXb)
{
    __shared__ __align__(16) unsigned short Ks[2][4096];   // [key64][d64] swizzled
    __shared__ __align__(16) unsigned short Vts[2][4096];  // [d64][key64] swizzled

    const int tid = threadIdx.x;
    const int l = tid & 63;
    const int w = tid >> 6;
    const int l31 = l & 31;
    const int hi = l >> 5;
    const int qt = blockIdx.x, h = blockIdx.y, b = blockIdx.z;

    // Q B-frags: B[col=q=l31][k=d] ; d = df*16 + hi*8 + e
    const size_t qrow = (size_t)(b * SEQ + qt * 128 + w * 32 + l31);
    bf16x8 qf[4];
#pragma unroll
    for (int df = 0; df < 4; ++df)
        qf[df] = *(const bf16x8*)&Qb[qrow * DIM + h * DPH + df * 16 + hi * 8];

    // staging mapping: sub-row = l>>3, slot s = l&7, source slot = s ^ sub
    const int sub = l >> 3, ss = (l & 7) ^ sub;
    const unsigned short* Kptr  = Kb  + (size_t)(b * SEQ) * DIM + h * DPH;
    const unsigned short* Vtptr = Vtb + ((size_t)(b * NH + h) * DPH) * SEQ;
    const unsigned long long* mbp = MB + b * 32;

    f32x16 ctx0 = {}, ctx1 = {};
    float lsum = 0.f;

    // prologue: stage kt=0 into buf 0 (each wave: rows w*16..w*16+15 of K and Vt)
    {
        const int r0 = w * 16, r1 = w * 16 + 8;
        stage16(Kptr + (size_t)(r0 + sub) * DIM + ss * 8, &Ks[0][r0 * 64]);
        stage16(Kptr + (size_t)(r1 + sub) * DIM + ss * 8, &Ks[0][r1 * 64]);
        stage16(Vtptr + (size_t)(r0 + sub) * SEQ + ss * 8, &Vts[0][r0 * 64]);
        stage16(Vtptr + (size_t)(r1 + sub) * SEQ + ss * 8, &Vts[0][r1 * 64]);
    }

    for (int kt = 0; kt < SEQ / 64; ++kt) {
        __syncthreads();  // buf[kt&1] staged; prior reads of buf[(kt+1)&1] done
        const int cur = kt & 1;
        if (kt + 1 < SEQ / 64) {
            const int nxt = cur ^ 1;
            const int r0 = w * 16, r1 = w * 16 + 8;
            const size_t ko = (size_t)((kt + 1) * 64);
            stage16(Kptr + (ko + r0 + sub) * DIM + ss * 8, &Ks[nxt][r0 * 64]);
            stage16(Kptr + (ko + r1 + sub) * DIM + ss * 8, &Ks[nxt][r1 * 64]);
            stage16(Vtptr + (size_t)(r0 + sub) * SEQ + ko + ss * 8, &Vts[nxt][r0 * 64]);
            stage16(Vtptr + (size_t)(r1 + sub) * SEQ + ko + ss * 8, &Vts[nxt][r1 * 64]);
        }

        // S^T = K @ Q^T : 2 key-row frags x 4 d-frags
        const char* kbase = (const char*)Ks[cur];
        f32x16 S0 = {}, S1 = {};
#pragma unroll
        for (int df = 0; df < 4; ++df) {
            const int so = ((df * 2 + hi) ^ (l31 & 7)) << 4;
            bf16x8 k0 = *(const bf16x8*)(kbase + l31 * 128 + so);
            bf16x8 k1 = *(const bf16x8*)(kbase + (32 + l31) * 128 + so);
            S0 = __builtin_amdgcn_mfma_f32_32x32x16_bf16(k0, qf[df], S0, 0, 0, 0);
            S1 = __builtin_amdgcn_mfma_f32_32x32x16_bf16(k1, qf[df], S1, 0, 0, 0);
        }

        // P = exp2(S) (q pre-scaled by log2e*scale); lane holds q=l31, 32 of 64 keys
        float p[32];
#pragma unroll
        for (int r = 0; r < 16; ++r) {
            p[r]      = __builtin_amdgcn_exp2f(S0[r]);
            p[16 + r] = __builtin_amdgcn_exp2f(S1[r]);
        }

        // mask (rare path; uniform branch — all-ones input skips)
        const unsigned long long bits = mbp[kt];
        if (bits != ~0ull) {
#pragma unroll
            for (int r = 0; r < 16; ++r) {
                const int key0 = (r & 3) + 8 * (r >> 2) + 4 * hi;
                p[r]      *= (float)((bits >> key0) & 1);
                p[16 + r] *= (float)((bits >> (32 + key0)) & 1);
            }
        }

#pragma unroll
        for (int r = 0; r < 32; ++r) lsum += p[r];

        // T12 pack: P (C-layout, key = (r&3)+8*(r>>2)+4*hi) -> PV A-frags.
        // Frag kf2 needs key = kf2*16 + hi*8 + e. Word words (2 keys each):
        //   word0: keys k0+0..1  (src lo-half, a = 2fh+hi)  word1: keys k0+2..3 (src lo)
        //   word2: keys k0+4..5  (src hi-half)              word3: keys k0+6..7 (src hi)
        // plswap(A=w[2fh], B=w[2fh+1]): A' = {A_lo, B_lo} -> per-lane w[2fh+hi]_lo = word0/1;
        //                               B' = {A_hi, B_hi} -> per-lane w[2fh+hi]_hi = word2/3.
        bf16x8 pa[4];
#pragma unroll
        for (int krow = 0; krow < 2; ++krow) {
            const float* pp = &p[krow * 16];
            unsigned w01[4], w23[4];
#pragma unroll
            for (int a = 0; a < 4; ++a) {
                w01[a] = cvtpk(pp[4 * a + 0], pp[4 * a + 1]);  // keys 8a+4hi+{0,1}
                w23[a] = cvtpk(pp[4 * a + 2], pp[4 * a + 3]);  // keys 8a+4hi+{2,3}
            }
#pragma unroll
            for (int fh = 0; fh < 2; ++fh) {
                unsigned A0 = w01[2 * fh], B0 = w01[2 * fh + 1];
                unsigned A1 = w23[2 * fh], B1 = w23[2 * fh + 1];
                plswap(A0, B0);  // A0 = word0, B0 = word2
                plswap(A1, B1);  // A1 = word1, B1 = word3
                u32x4 t = {A0, A1, B0, B1};
                union { u32x4 u; bf16x8 v; } cvt;
                cvt.u = t;
                pa[krow * 2 + fh] = cvt.v;
            }
        }

        // ctx += P @ V : B-frags from swizzled Vt [d][key]
        const char* vbase = (const char*)Vts[cur];
#pragma unroll
        for (int kf2 = 0; kf2 < 4; ++kf2) {
            const int so = ((kf2 * 2 + hi) ^ (l31 & 7)) << 4;
            bf16x8 v0 = *(const bf16x8*)(vbase + l31 * 128 + so);
            bf16x8 v1 = *(const bf16x8*)(vbase + (32 + l31) * 128 + so);
            ctx0 = __builtin_amdgcn_mfma_f32_32x32x16_bf16(pa[kf2], v0, ctx0, 0, 0, 0);
            ctx1 = __builtin_amdgcn_mfma_f32_32x32x16_bf16(pa[kf2], v1, ctx1, 0, 0, 0);
        }
    }

    // finalize: full row-sum (other 32 keys live in lane^32), then scatter inv by q
    lsum += __shfl_xor(lsum, 32);
    const float inv = 1.0f / lsum;  // lane holds inv for q = l31

    const size_t orow0 = (size_t)(b * SEQ + qt * 128 + w * 32);
#pragma unroll
    for (int r = 0; r < 16; ++r) {
        const int q = (r & 3) + 8 * (r >> 2) + 4 * hi;
        const float invr = __shfl(inv, q);
        const size_t ro = (orow0 + q) * DIM + h * DPH;
        CTXb[ro + l31]      = f2bf(ctx0[r] * invr);
        CTXb[ro + 32 + l31] = f2bf(ctx1[r] * invr);
    }
}

// ---------------- launch ----------------
extern "C" void kernel_launch(void* const* d_in, const int* in_sizes, int n_in,
                              void* d_out, int out_size, void* d_ws, size_t ws_size,
                              hipStream_t stream)
{
    const float* x    = (const float*)d_in[0];
    const int*   mask = (const int*)d_in[1];
    const float* Wq   = (const float*)d_in[2];
    const float* bq   = (const float*)d_in[3];
    const float* Wk   = (const float*)d_in[4];
    const float* bk   = (const float*)d_in[5];
    const float* Wv   = (const float*)d_in[6];
    const float* bv   = (const float*)d_in[7];
    const float* Wo   = (const float*)d_in[8];
    const float* bo   = (const float*)d_in[9];
    const float* scale = (const float*)d_in[10];
    float* out = (float*)d_out;

    char* p = (char*)d_ws;
    unsigned short* Xb  = (unsigned short*)p; p += (size_t)MTOT * DIM * 2;
    unsigned short* Wqt = (unsigned short*)p; p += (size_t)DIM * DIM * 2;
    unsigned short* Wkt = (unsigned short*)p; p += (size_t)DIM * DIM * 2;
    unsigned short* Wvt = (unsigned short*)p; p += (size_t)DIM * DIM * 2;
    unsigned short* Wot = (unsigned short*)p; p += (size_t)DIM * DIM * 2;
    unsigned short* Qb  = (unsigned short*)p; p += (size_t)MTOT * DIM * 2;
    unsigned short* Kb  = (unsigned short*)p; p += (size_t)MTOT * DIM * 2;
    unsigned short* Vtb = (unsigned short*)p; p += (size_t)MTOT * DIM * 2;  // [b,h,d,seq]
    unsigned short* CTXb = (unsigned short*)p; p += (size_t)MTOT * DIM * 2;
    unsigned long long* MBits = (unsigned long long*)p;                      // 64 words

    cast_x<<<dim3(MTOT * DIM / 4 / 256), 256, 0, stream>>>(x, Xb);
    prep_w<<<dim3(32, 32, 4), 256, 0, stream>>>(Wq, Wk, Wv, Wo, Wqt, Wkt, Wvt, Wot);
    pack_mask<<<dim3(16), 256, 0, stream>>>(mask, MBits);
    qkv_gemm<<<dim3(DIM / 128, MTOT / 128, 3), 256, 0, stream>>>(
        Xb, Wqt, Wkt, Wvt, bq, bk, bv, Qb, Kb, Vtb);
    norm_qk<<<dim3(MTOT), 256, 0, stream>>>(Qb, Kb, scale);
    attn<<<dim3(SEQ / 128, NH, 2), 256, 0, stream>>>(Qb, Kb, Vtb, MBits, CTXb);
    o_gemm<<<dim3(DIM / 128, MTOT / 128, 1), 256, 0, stream>>>(CTXb, Wot, bo, out);
}

// Round 7
// 239.619 us; speedup vs baseline: 4.8541x; 1.0638x over previous
//
#include <hip/hip_runtime.h>
#include <math.h>

#define SEQ 2048
#define DIM 1024
#define NH 16
#define DPH 64
#define MTOT 4096  // BS2 * SEQ

typedef __attribute__((ext_vector_type(8))) short bf16x8;
typedef __attribute__((ext_vector_type(4))) float f32x4;
typedef __attribute__((ext_vector_type(16))) float f32x16;
typedef __attribute__((ext_vector_type(4))) unsigned int u32x4;

__device__ __forceinline__ unsigned short f2bf(float f) {
    unsigned int u = __float_as_uint(f);
    return (unsigned short)((u + 0x7FFFu + ((u >> 16) & 1u)) >> 16);
}
__device__ __forceinline__ float bf2f(unsigned short h) {
    return __uint_as_float(((unsigned int)h) << 16);
}

__device__ __forceinline__ void stage16(const void* g, void* lds) {
    __builtin_amdgcn_global_load_lds((const __attribute__((address_space(1))) void*)g,
                                     (__attribute__((address_space(3))) void*)lds,
                                     16, 0, 0);
}

__device__ __forceinline__ unsigned cvtpk(float lo, float hi) {
    unsigned w;
    asm("v_cvt_pk_bf16_f32 %0, %1, %2" : "=v"(w) : "v"(lo), "v"(hi));
    return w;
}
// v_permlane32_swap_b32 A, B:  A' = {A_lo, B_lo}, B' = {A_hi, B_hi}
__device__ __forceinline__ void plswap(unsigned &a, unsigned &b) {
    asm("v_permlane32_swap_b32 %0, %1" : "+v"(a), "+v"(b));
}

// XCD-aware bijective remap (nb % 8 == 0). Dispatch order: x fastest.
// Logical order inside an XCD: all (x,z) of a y-panel before the next y.
__device__ __forceinline__ void xcd_remap(int gx, int gy, int gz,
                                          int &x, int &y, int &z)
{
    const int h = (blockIdx.z * gy + blockIdx.y) * gx + blockIdx.x;
    const int nb = gx * gy * gz;
    const int chunk = nb >> 3;
    const int l = (h & 7) * chunk + (h >> 3);
    const int P = gx * gz;
    y = l / P;
    const int r = l - y * P;
    z = r / gx;
    x = r - z * gx;
}

// ---------------- prep: cast x to bf16 ----------------
__global__ __launch_bounds__(256) void cast_x(const float* __restrict__ X,
                                              unsigned short* __restrict__ Xb)
{
    size_t i = (size_t)blockIdx.x * 256 + threadIdx.x;
    float4 v = *(const float4*)&X[i * 4];
    ushort4 o;
    o.x = f2bf(v.x); o.y = f2bf(v.y); o.z = f2bf(v.z); o.w = f2bf(v.w);
    *(ushort4*)&Xb[i * 4] = o;
}

// ---------------- prep: transpose-cast W [k][n] f32 -> Wt [n][k] bf16 ----------------
__global__ __launch_bounds__(256) void prep_w(
    const float* __restrict__ Wq, const float* __restrict__ Wk,
    const float* __restrict__ Wv, const float* __restrict__ Wo,
    unsigned short* __restrict__ Wqt, unsigned short* __restrict__ Wkt,
    unsigned short* __restrict__ Wvt, unsigned short* __restrict__ Wot)
{
    const float* W; unsigned short* Wt;
    switch (blockIdx.z) {
        case 0: W = Wq; Wt = Wqt; break;
        case 1: W = Wk; Wt = Wkt; break;
        case 2: W = Wv; Wt = Wvt; break;
        default: W = Wo; Wt = Wot; break;
    }
    __shared__ float T[32][33];
    const int t = threadIdx.x;
    const int kt0 = blockIdx.y * 32;
    const int nt0 = blockIdx.x * 32;
    const int r = t >> 3, c4 = (t & 7) * 4;
    float4 v = *(const float4*)&W[(size_t)(kt0 + r) * DIM + nt0 + c4];
    T[r][c4 + 0] = v.x; T[r][c4 + 1] = v.y; T[r][c4 + 2] = v.z; T[r][c4 + 3] = v.w;
    __syncthreads();
    ushort4 o;
    o.x = f2bf(T[c4 + 0][r]);
    o.y = f2bf(T[c4 + 1][r]);
    o.z = f2bf(T[c4 + 2][r]);
    o.w = f2bf(T[c4 + 3][r]);
    *(ushort4*)&Wt[(size_t)(nt0 + r) * DIM + kt0 + c4] = o;
}

// ---------------- pack mask bits ----------------
__global__ __launch_bounds__(256) void pack_mask(const int* __restrict__ mask,
                                                 unsigned long long* __restrict__ MB)
{
    const int w = blockIdx.x * 4 + (threadIdx.x >> 6);
    const int lane = threadIdx.x & 63;
    const int b = w >> 5, kt = w & 31;
    int m = mask[b * SEQ + kt * 64 + lane];
    unsigned long long bits = __ballot(m != 0);
    if (lane == 0) MB[w] = bits;
}

// ---------------- bf16 MFMA GEMM core, double-buffered 2-phase ----------------
// mode 0: normalized bf16 out (per-head L2 norm over the 64-col head; qs factor)
// mode 1: bf16 transposed V out [b,h,d,seq]
// mode 2: fp32 out + bias
__device__ __forceinline__ void gemm_core(
    const unsigned short* __restrict__ Ab, const unsigned short* __restrict__ Bt,
    const float* __restrict__ bias, unsigned short* __restrict__ Cb,
    float* __restrict__ Cf, int mode, int bx, int by, float qs)
{
    __shared__ __align__(16) unsigned short As[2][4096];
    __shared__ __align__(16) unsigned short Bs[2][4096];

    const int tid = threadIdx.x;
    const int l = tid & 63;
    const int w = tid >> 6;
    const int wm = w >> 1, wn = w & 1;
    const int lr = l & 15, lg = l >> 4;
    const int bm = by * 128;
    const int bn = bx * 128;

    const unsigned short* a_src0 = Ab + (size_t)(bm + (2 * w) * 16 + lr) * DIM + lg * 8;
    const unsigned short* a_src1 = Ab + (size_t)(bm + (2 * w + 1) * 16 + lr) * DIM + lg * 8;
    const unsigned short* b_src0 = Bt + (size_t)(bn + (2 * w) * 16 + lr) * DIM + lg * 8;
    const unsigned short* b_src1 = Bt + (size_t)(bn + (2 * w + 1) * 16 + lr) * DIM + lg * 8;

    f32x4 acc[4][4];
#pragma unroll
    for (int i = 0; i < 4; ++i)
#pragma unroll
        for (int j = 0; j < 4; ++j) acc[i][j] = (f32x4){0.f, 0.f, 0.f, 0.f};

    // prologue: stage K-step 0 into buf 0
    stage16(a_src0, &As[0][(2 * w) * 512]);
    stage16(a_src1, &As[0][(2 * w + 1) * 512]);
    stage16(b_src0, &Bs[0][(2 * w) * 512]);
    stage16(b_src1, &Bs[0][(2 * w + 1) * 512]);

    int t = 0;
    for (int kk = 0; kk < DIM; kk += 32) {
        __syncthreads();  // drains stage(buf t); prior reads of buf t^1 done
        if (kk + 32 < DIM) {
            const int nxt = t ^ 1;
            stage16(a_src0 + kk + 32, &As[nxt][(2 * w) * 512]);
            stage16(a_src1 + kk + 32, &As[nxt][(2 * w + 1) * 512]);
            stage16(b_src0 + kk + 32, &Bs[nxt][(2 * w) * 512]);
            stage16(b_src1 + kk + 32, &Bs[nxt][(2 * w + 1) * 512]);
        }
        bf16x8 aF[4], bF[4];
#pragma unroll
        for (int i = 0; i < 4; ++i) {
            aF[i] = *(const bf16x8*)&As[t][(wm * 4 + i) * 512 + l * 8];
            bF[i] = *(const bf16x8*)&Bs[t][(wn * 4 + i) * 512 + l * 8];
        }
#pragma unroll
        for (int i = 0; i < 4; ++i)
#pragma unroll
            for (int j = 0; j < 4; ++j)
                acc[i][j] = __builtin_amdgcn_mfma_f32_16x16x32_bf16(aF[i], bF[j], acc[i][j], 0, 0, 0);
        t ^= 1;
    }

    // bias add (bias[n] per column)
    float bvj[4];
#pragma unroll
    for (int j = 0; j < 4; ++j) bvj[j] = bias[bn + wn * 64 + j * 16 + lr];
#pragma unroll
    for (int i = 0; i < 4; ++i)
#pragma unroll
        for (int j = 0; j < 4; ++j)
#pragma unroll
            for (int p = 0; p < 4; ++p) acc[i][j][p] += bvj[j];

    if (mode == 0) {
        // fused per-head L2 norm: head = 64 cols = j regs x 16 lr lanes (within wave)
#pragma unroll
        for (int i = 0; i < 4; ++i) {
            float scl[4];
#pragma unroll
            for (int p = 0; p < 4; ++p) {
                float s = 0.f;
#pragma unroll
                for (int j = 0; j < 4; ++j) s = fmaf(acc[i][j][p], acc[i][j][p], s);
                s += __shfl_xor(s, 1);
                s += __shfl_xor(s, 2);
                s += __shfl_xor(s, 4);
                s += __shfl_xor(s, 8);
                scl[p] = qs / fmaxf(sqrtf(s), 1e-12f);
            }
            const int m0 = bm + wm * 64 + i * 16 + lg * 4;
#pragma unroll
            for (int j = 0; j < 4; ++j) {
                const int n = bn + wn * 64 + j * 16 + lr;
#pragma unroll
                for (int p = 0; p < 4; ++p)
                    Cb[(size_t)(m0 + p) * DIM + n] = f2bf(acc[i][j][p] * scl[p]);
            }
        }
    } else if (mode == 1) {
#pragma unroll
        for (int i = 0; i < 4; ++i) {
            const int m0 = bm + wm * 64 + i * 16 + lg * 4;
            const int b = m0 >> 11, s = m0 & 2047;
#pragma unroll
            for (int j = 0; j < 4; ++j) {
                const int n = bn + wn * 64 + j * 16 + lr;
                const int h = n >> 6, d = n & 63;
                ushort4 o;
                o.x = f2bf(acc[i][j][0]);
                o.y = f2bf(acc[i][j][1]);
                o.z = f2bf(acc[i][j][2]);
                o.w = f2bf(acc[i][j][3]);
                *(ushort4*)&Cb[((size_t)((b * NH + h) * DPH + d)) * SEQ + s] = o;
            }
        }
    } else {
#pragma unroll
        for (int i = 0; i < 4; ++i) {
            const int m0 = bm + wm * 64 + i * 16 + lg * 4;
#pragma unroll
            for (int j = 0; j < 4; ++j) {
                const int n = bn + wn * 64 + j * 16 + lr;
#pragma unroll
                for (int p = 0; p < 4; ++p)
                    Cf[(size_t)(m0 + p) * DIM + n] = acc[i][j][p];
            }
        }
    }
}

__global__ __launch_bounds__(256) void qkv_gemm(
    const unsigned short* __restrict__ Xb,
    const unsigned short* __restrict__ Wqt, const unsigned short* __restrict__ Wkt,
    const unsigned short* __restrict__ Wvt,
    const float* __restrict__ bq, const float* __restrict__ bk, const float* __restrict__ bv,
    const float* __restrict__ scale_p,
    unsigned short* __restrict__ Qb, unsigned short* __restrict__ Kb,
    unsigned short* __restrict__ Vtb)
{
    int x, y, z;
    xcd_remap(8, 32, 3, x, y, z);
    if (z == 0)
        gemm_core(Xb, Wqt, bq, Qb, nullptr, 0, x, y, scale_p[0] * 1.44269504088896340736f);
    else if (z == 1)
        gemm_core(Xb, Wkt, bk, Kb, nullptr, 0, x, y, 1.0f);
    else
        gemm_core(Xb, Wvt, bv, Vtb, nullptr, 1, x, y, 1.0f);
}

__global__ __launch_bounds__(256) void o_gemm(
    const unsigned short* __restrict__ Ab, const unsigned short* __restrict__ Wot,
    const float* __restrict__ bo, float* __restrict__ Out)
{
    int x, y, z;
    xcd_remap(8, 32, 1, x, y, z);
    gemm_core(Ab, Wot, bo, nullptr, Out, 2, x, y, 1.0f);
}

// ---------------- flash attention, 32x32x16 MFMA, swapped QK^T, no-max softmax ----------------
__global__ __launch_bounds__(256) void attn(
    const unsigned short* __restrict__ Qb, const unsigned short* __restrict__ Kb,
    const unsigned short* __restrict__ Vtb, const unsigned long long* __restrict__ MB,
    unsigned short* __restrict__ CTXb)
{
    __shared__ __align__(16) unsigned short Ks[2][4096];   // [key64][d64] swizzled
    __shared__ __align__(16) unsigned short Vts[2][4096];  // [d64][key64] swizzled

    const int tid = threadIdx.x;
    const int l = tid & 63;
    const int w = tid >> 6;
    const int l31 = l & 31;
    const int hi = l >> 5;

    // XCD remap: group the 16 q-tiles of each (head,batch) on one XCD
    int qt, h, b;
    {
        const int hh = (blockIdx.z * 16 + blockIdx.y) * 16 + blockIdx.x;
        const int ll = (hh & 7) * 64 + (hh >> 3);
        qt = ll & 15;
        const int g = ll >> 4;
        h = g & 15;
        b = g >> 4;
    }

    const size_t qrow = (size_t)(b * SEQ + qt * 128 + w * 32 + l31);
    bf16x8 qf[4];
#pragma unroll
    for (int df = 0; df < 4; ++df)
        qf[df] = *(const bf16x8*)&Qb[qrow * DIM + h * DPH + df * 16 + hi * 8];

    const int sub = l >> 3, ss = (l & 7) ^ sub;
    const unsigned short* Kptr  = Kb  + (size_t)(b * SEQ) * DIM + h * DPH;
    const unsigned short* Vtptr = Vtb + ((size_t)(b * NH + h) * DPH) * SEQ;
    const unsigned long long* mbp = MB + b * 32;

    f32x16 ctx0 = {}, ctx1 = {};
    float lsum = 0.f;

    {
        const int r0 = w * 16, r1 = w * 16 + 8;
        stage16(Kptr + (size_t)(r0 + sub) * DIM + ss * 8, &Ks[0][r0 * 64]);
        stage16(Kptr + (size_t)(r1 + sub) * DIM + ss * 8, &Ks[0][r1 * 64]);
        stage16(Vtptr + (size_t)(r0 + sub) * SEQ + ss * 8, &Vts[0][r0 * 64]);
        stage16(Vtptr + (size_t)(r1 + sub) * SEQ + ss * 8, &Vts[0][r1 * 64]);
    }

    for (int kt = 0; kt < SEQ / 64; ++kt) {
        __syncthreads();
        const int cur = kt & 1;
        if (kt + 1 < SEQ / 64) {
            const int nxt = cur ^ 1;
            const int r0 = w * 16, r1 = w * 16 + 8;
            const size_t ko = (size_t)((kt + 1) * 64);
            stage16(Kptr + (ko + r0 + sub) * DIM + ss * 8, &Ks[nxt][r0 * 64]);
            stage16(Kptr + (ko + r1 + sub) * DIM + ss * 8, &Ks[nxt][r1 * 64]);
            stage16(Vtptr + (size_t)(r0 + sub) * SEQ + ko + ss * 8, &Vts[nxt][r0 * 64]);
            stage16(Vtptr + (size_t)(r1 + sub) * SEQ + ko + ss * 8, &Vts[nxt][r1 * 64]);
        }

        const char* kbase = (const char*)Ks[cur];
        f32x16 S0 = {}, S1 = {};
#pragma unroll
        for (int df = 0; df < 4; ++df) {
            const int so = ((df * 2 + hi) ^ (l31 & 7)) << 4;
            bf16x8 k0 = *(const bf16x8*)(kbase + l31 * 128 + so);
            bf16x8 k1 = *(const bf16x8*)(kbase + (32 + l31) * 128 + so);
            S0 = __builtin_amdgcn_mfma_f32_32x32x16_bf16(k0, qf[df], S0, 0, 0, 0);
            S1 = __builtin_amdgcn_mfma_f32_32x32x16_bf16(k1, qf[df], S1, 0, 0, 0);
        }

        float p[32];
#pragma unroll
        for (int r = 0; r < 16; ++r) {
            p[r]      = __builtin_amdgcn_exp2f(S0[r]);
            p[16 + r] = __builtin_amdgcn_exp2f(S1[r]);
        }

        const unsigned long long bits = mbp[kt];
        if (bits != ~0ull) {
#pragma unroll
            for (int r = 0; r < 16; ++r) {
                const int key0 = (r & 3) + 8 * (r >> 2) + 4 * hi;
                p[r]      *= (float)((bits >> key0) & 1);
                p[16 + r] *= (float)((bits >> (32 + key0)) & 1);
            }
        }

#pragma unroll
        for (int r = 0; r < 32; ++r) lsum += p[r];

        bf16x8 pa[4];
#pragma unroll
        for (int krow = 0; krow < 2; ++krow) {
            const float* pp = &p[krow * 16];
            unsigned w01[4], w23[4];
#pragma unroll
            for (int a = 0; a < 4; ++a) {
                w01[a] = cvtpk(pp[4 * a + 0], pp[4 * a + 1]);
                w23[a] = cvtpk(pp[4 * a + 2], pp[4 * a + 3]);
            }
#pragma unroll
            for (int fh = 0; fh < 2; ++fh) {
                unsigned A0 = w01[2 * fh], B0 = w01[2 * fh + 1];
                unsigned A1 = w23[2 * fh], B1 = w23[2 * fh + 1];
                plswap(A0, B0);
                plswap(A1, B1);
                u32x4 tt = {A0, A1, B0, B1};
                union { u32x4 u; bf16x8 v; } cvt;
                cvt.u = tt;
                pa[krow * 2 + fh] = cvt.v;
            }
        }

        const char* vbase = (const char*)Vts[cur];
#pragma unroll
        for (int kf2 = 0; kf2 < 4; ++kf2) {
            const int so = ((kf2 * 2 + hi) ^ (l31 & 7)) << 4;
            bf16x8 v0 = *(const bf16x8*)(vbase + l31 * 128 + so);
            bf16x8 v1 = *(const bf16x8*)(vbase + (32 + l31) * 128 + so);
            ctx0 = __builtin_amdgcn_mfma_f32_32x32x16_bf16(pa[kf2], v0, ctx0, 0, 0, 0);
            ctx1 = __builtin_amdgcn_mfma_f32_32x32x16_bf16(pa[kf2], v1, ctx1, 0, 0, 0);
        }
    }

    lsum += __shfl_xor(lsum, 32);
    const float inv = 1.0f / lsum;

    const size_t orow0 = (size_t)(b * SEQ + qt * 128 + w * 32);
#pragma unroll
    for (int r = 0; r < 16; ++r) {
        const int q = (r & 3) + 8 * (r >> 2) + 4 * hi;
        const float invr = __shfl(inv, q);
        const size_t ro = (orow0 + q) * DIM + h * DPH;
        CTXb[ro + l31]      = f2bf(ctx0[r] * invr);
        CTXb[ro + 32 + l31] = f2bf(ctx1[r] * invr);
    }
}

// ---------------- launch ----------------
extern "C" void kernel_launch(void* const* d_in, const int* in_sizes, int n_in,
                              void* d_out, int out_size, void* d_ws, size_t ws_size,
                              hipStream_t stream)
{
    const float* x    = (const float*)d_in[0];
    const int*   mask = (const int*)d_in[1];
    const float* Wq   = (const float*)d_in[2];
    const float* bq   = (const float*)d_in[3];
    const float* Wk   = (const float*)d_in[4];
    const float* bk   = (const float*)d_in[5];
    const float* Wv   = (const float*)d_in[6];
    const float* bv   = (const float*)d_in[7];
    const float* Wo   = (const float*)d_in[8];
    const float* bo   = (const float*)d_in[9];
    const float* scale = (const float*)d_in[10];
    float* out = (float*)d_out;

    char* p = (char*)d_ws;
    unsigned short* Xb  = (unsigned short*)p; p += (size_t)MTOT * DIM * 2;
    unsigned short* Wqt = (unsigned short*)p; p += (size_t)DIM * DIM * 2;
    unsigned short* Wkt = (unsigned short*)p; p += (size_t)DIM * DIM * 2;
    unsigned short* Wvt = (unsigned short*)p; p += (size_t)DIM * DIM * 2;
    unsigned short* Wot = (unsigned short*)p; p += (size_t)DIM * DIM * 2;
    unsigned short* Qb  = (unsigned short*)p; p += (size_t)MTOT * DIM * 2;
    unsigned short* Kb  = (unsigned short*)p; p += (size_t)MTOT * DIM * 2;
    unsigned short* Vtb = (unsigned short*)p; p += (size_t)MTOT * DIM * 2;  // [b,h,d,seq]
    unsigned short* CTXb = (unsigned short*)p; p += (size_t)MTOT * DIM * 2;
    unsigned long long* MBits = (unsigned long long*)p;                      // 64 words

    cast_x<<<dim3(MTOT * DIM / 4 / 256), 256, 0, stream>>>(x, Xb);
    prep_w<<<dim3(32, 32, 4), 256, 0, stream>>>(Wq, Wk, Wv, Wo, Wqt, Wkt, Wvt, Wot);
    pack_mask<<<dim3(16), 256, 0, stream>>>(mask, MBits);
    qkv_gemm<<<dim3(8, 32, 3), 256, 0, stream>>>(
        Xb, Wqt, Wkt, Wvt, bq, bk, bv, scale, Qb, Kb, Vtb);
    attn<<<dim3(16, 16, 2), 256, 0, stream>>>(Qb, Kb, Vtb, MBits, CTXb);
    o_gemm<<<dim3(8, 32, 1), 256, 0, stream>>>(CTXb, Wot, bo, out);
}